// Round 1
// baseline (456.898 us; speedup 1.0000x reference)
//
#include <hip/hip_runtime.h>

#define NS   125      // n_support
#define NW   5        // n_way
#define NQ   2048
#define DD   8192
#define CREG 0.1f
#define PGD_ITERS 128

// ws float offsets
#define OFF_PART 0          // 64 * 15625 = 1,000,000 floats
#define OFF_K    1000000    // 15625
#define OFF_QP3  1016000    // 625
#define OFF_W    1017000    // 5*8192 = 40960
// total ~4.24 MB of ws

// ---------------- Gram partials: K_partial[c] = S[:, c*128:(c+1)*128] chunk ----------------
__global__ __launch_bounds__(256) void gram_partial(const float* __restrict__ support,
                                                    float* __restrict__ part) {
    __shared__ __align__(16) float Sd[128 * 132];  // [d][s], pitch 132 (4-way max conflicts, 16B-aligned rows)
    const int tid = threadIdx.x;
    const int blk = blockIdx.x;
    const int d0 = blk * 128;
    for (int idx = tid; idx < 128 * 128; idx += 256) {
        int s = idx >> 7, dj = idx & 127;
        float g = (s < NS) ? support[(size_t)s * DD + d0 + dj] : 0.f;
        Sd[dj * 132 + s] = g;
    }
    __syncthreads();
    const int tx = tid & 15, ty = tid >> 4;   // 8x8 output tile per thread over 128x128 (>=125)
    float acc[8][8];
#pragma unroll
    for (int i = 0; i < 8; i++)
#pragma unroll
        for (int j = 0; j < 8; j++) acc[i][j] = 0.f;
    for (int d = 0; d < 128; ++d) {
        float4 a0 = *(const float4*)&Sd[d * 132 + tx * 8];
        float4 a1 = *(const float4*)&Sd[d * 132 + tx * 8 + 4];
        float4 b0 = *(const float4*)&Sd[d * 132 + ty * 8];
        float4 b1 = *(const float4*)&Sd[d * 132 + ty * 8 + 4];
        float av[8] = {a0.x, a0.y, a0.z, a0.w, a1.x, a1.y, a1.z, a1.w};
        float bv[8] = {b0.x, b0.y, b0.z, b0.w, b1.x, b1.y, b1.z, b1.w};
#pragma unroll
        for (int i = 0; i < 8; i++)
#pragma unroll
            for (int j = 0; j < 8; j++) acc[i][j] += av[i] * bv[j];
    }
    float* dst = part + (size_t)blk * (NS * NS);
    for (int i = 0; i < 8; i++) {
        int gi = tx * 8 + i;
        if (gi >= NS) continue;
        for (int j = 0; j < 8; j++) {
            int gj = ty * 8 + j;
            if (gj < NS) dst[gi * NS + gj] = acc[i][j];
        }
    }
}

// ---------------- Reduce partials -> K ----------------
__global__ __launch_bounds__(256) void gram_reduce(const float* __restrict__ part,
                                                   float* __restrict__ Kg) {
    int t = blockIdx.x * 256 + threadIdx.x;
    if (t < NS * NS) {
        float s = 0.f;
        for (int c = 0; c < 64; ++c) s += part[(size_t)c * (NS * NS) + t];
        Kg[t] = s;
    }
}

// ---------------- QP via projected gradient descent (single block) ----------------
// min 0.5 z^T G z + e^T z,  G = kron(K,I5)+I,  s.t. z <= h (h = C*y1h), sum_a z[s,a] = 0
// kappa(G) ~ 1.65 => PGD with eta = 1/RowSumBound contracts ~0.63/iter; 128 iters => converged to fp32 noise.
__global__ __launch_bounds__(256) void qp_solve(const float* __restrict__ Kg,
                                                const int* __restrict__ labels,
                                                float* __restrict__ qp3,
                                                float* __restrict__ outNumSv) {
    __shared__ __align__(16) float zc[NW][128];  // z columns, padded to 128 (pad = 0)
    __shared__ float red[128 * NW];              // matvec partials from p==1 (also reused for gershgorin)
    __shared__ float rs[128];
    __shared__ float eta_sh;
    __shared__ int svcount;

    const int tid = threadIdx.x;
    const int s = tid >> 1;       // sample 0..127
    const int p = tid & 1;        // j-half

    // K row half into registers (invariant across iterations)
    float kr[64];
#pragma unroll
    for (int j = 0; j < 64; ++j) {
        int col = p * 64 + j;
        kr[j] = (s < NS && col < NS) ? Kg[s * NS + col] : 0.f;
    }
    // init z (incl. padding) to 0
    for (int idx = tid; idx < NW * 128; idx += 256) ((float*)zc)[idx] = 0.f;
    // Gershgorin row-sum bound on lambda_max(K)
    float rsum = 0.f;
#pragma unroll
    for (int j = 0; j < 64; ++j) rsum += fabsf(kr[j]);
    red[tid] = rsum;
    if (tid == 0) svcount = 0;
    __syncthreads();
    if (p == 0 && s < NS) rs[s] = red[2 * s] + red[2 * s + 1];
    __syncthreads();
    if (tid == 0) {
        float m = 0.f;
        for (int i = 0; i < NS; ++i) m = fmaxf(m, rs[i]);
        eta_sh = 1.0f / (m + 1.0f);   // G = K(+kron) + I
    }
    __syncthreads();
    const float eta = eta_sh;
    const int lab = (s < NS) ? labels[s] : 0;
    float z[NW];
#pragma unroll
    for (int a = 0; a < NW; a++) z[a] = 0.f;

    for (int it = 0; it < PGD_ITERS; ++it) {
        // matvec: this thread's half of (K z)[s, :]
        float acc[NW] = {0.f, 0.f, 0.f, 0.f, 0.f};
        const int jb0 = p * 64;
#pragma unroll
        for (int c = 0; c < 16; ++c) {
            const int jb = jb0 + c * 4;
            float k0 = kr[c * 4], k1 = kr[c * 4 + 1], k2 = kr[c * 4 + 2], k3 = kr[c * 4 + 3];
            float4 z0 = *(const float4*)&zc[0][jb];
            float4 z1 = *(const float4*)&zc[1][jb];
            float4 z2 = *(const float4*)&zc[2][jb];
            float4 z3 = *(const float4*)&zc[3][jb];
            float4 z4 = *(const float4*)&zc[4][jb];
            acc[0] += k0 * z0.x + k1 * z0.y + k2 * z0.z + k3 * z0.w;
            acc[1] += k0 * z1.x + k1 * z1.y + k2 * z1.z + k3 * z1.w;
            acc[2] += k0 * z2.x + k1 * z2.y + k2 * z2.z + k3 * z2.w;
            acc[3] += k0 * z3.x + k1 * z3.y + k2 * z3.z + k3 * z3.w;
            acc[4] += k0 * z4.x + k1 * z4.y + k2 * z4.z + k3 * z4.w;
        }
        if (p == 1) {
#pragma unroll
            for (int a = 0; a < NW; a++) red[s * NW + a] = acc[a];
        }
        __syncthreads();
        if (p == 0 && s < NS) {
            float v[NW], h[NW];
#pragma unroll
            for (int a = 0; a < NW; a++) {
                float kz = acc[a] + red[s * NW + a];
                float g = kz + z[a] - ((a == lab) ? 1.f : 0.f);   // Gz + e
                v[a] = z[a] - eta * g;
                h[a] = (a == lab) ? CREG : 0.f;
            }
            // exact projection onto {sum_a z = 0, z <= h}: Newton on g(tau)=sum min(v-tau,h)
            float tau = fmaxf(fmaxf(fmaxf(v[0], v[1]), fmaxf(v[2], v[3])), v[4]);  // g(tau0) <= 0
#pragma unroll
            for (int n = 0; n < 7; ++n) {
                float g = 0.f, nf = 0.f;
#pragma unroll
                for (int a = 0; a < NW; a++) {
                    float d = v[a] - tau;
                    bool fr = (d <= h[a]);
                    g += fr ? d : h[a];
                    nf += fr ? 1.f : 0.f;
                }
                tau += g / nf;  // nf >= 1 guaranteed on the Newton path
            }
#pragma unroll
            for (int a = 0; a < NW; a++) {
                z[a] = fminf(v[a] - tau, h[a]);
                zc[a][s] = z[a];
            }
        }
        __syncthreads();
    }

    // epilogue: num_sv + qp3 out
    if (p == 0 && s < NS) {
        float m = fmaxf(fmaxf(fmaxf(z[0], z[1]), fmaxf(z[2], z[3])), z[4]);
        if (m > 0.001f) atomicAdd(&svcount, 1);
#pragma unroll
        for (int a = 0; a < NW; a++) qp3[s * NW + a] = z[a];
    }
    __syncthreads();
    if (tid == 0) *outNumSv = (float)svcount;
}

// ---------------- W[a][d] = sum_s support[s][d] * qp3[s][a] ----------------
__global__ __launch_bounds__(256) void w_kernel(const float* __restrict__ support,
                                                const float* __restrict__ qp3,
                                                float* __restrict__ W) {
    __shared__ float q3[NS * NW];
    const int tid = threadIdx.x;
    for (int i = tid; i < NS * NW; i += 256) q3[i] = qp3[i];
    __syncthreads();
    const int d = blockIdx.x * 256 + tid;
    float acc[NW] = {0.f, 0.f, 0.f, 0.f, 0.f};
    for (int sld = 0; sld < NS; ++sld) {
        float sv = support[(size_t)sld * DD + d];
#pragma unroll
        for (int a = 0; a < NW; a++) acc[a] += sv * q3[sld * NW + a];
    }
#pragma unroll
    for (int a = 0; a < NW; a++) W[(size_t)a * DD + d] = acc[a];
}

// ---------------- logits[q][a] = scale * sum_d query[q][d] * W[a][d] ----------------
// one wave per 2 queries; lanes split d; butterfly reduce
__global__ __launch_bounds__(256) void logits_kernel(const float* __restrict__ query,
                                                     const float* __restrict__ W,
                                                     const float* __restrict__ scale,
                                                     float* __restrict__ out) {
    const int tid = threadIdx.x;
    const int wave = tid >> 6, lane = tid & 63;
    const int q0 = blockIdx.x * 8 + wave * 2;
    const int q1 = q0 + 1;
    float a0[NW] = {0.f, 0.f, 0.f, 0.f, 0.f};
    float a1[NW] = {0.f, 0.f, 0.f, 0.f, 0.f};
    const float4* qp0 = (const float4*)(query + (size_t)q0 * DD);
    const float4* qp1 = (const float4*)(query + (size_t)q1 * DD);
    for (int it = 0; it < 32; ++it) {
        int dv = it * 64 + lane;  // float4 index, 2048 total
        float4 qv0 = qp0[dv];
        float4 qv1 = qp1[dv];
#pragma unroll
        for (int a = 0; a < NW; a++) {
            float4 wv = ((const float4*)(W + (size_t)a * DD))[dv];
            a0[a] += qv0.x * wv.x + qv0.y * wv.y + qv0.z * wv.z + qv0.w * wv.w;
            a1[a] += qv1.x * wv.x + qv1.y * wv.y + qv1.z * wv.z + qv1.w * wv.w;
        }
    }
#pragma unroll
    for (int off = 32; off; off >>= 1) {
#pragma unroll
        for (int a = 0; a < NW; a++) {
            a0[a] += __shfl_xor(a0[a], off);
            a1[a] += __shfl_xor(a1[a], off);
        }
    }
    if (lane == 0) {
        float sc = scale[0];
#pragma unroll
        for (int a = 0; a < NW; a++) out[q0 * NW + a] = sc * a0[a];
#pragma unroll
        for (int a = 0; a < NW; a++) out[q1 * NW + a] = sc * a1[a];
    }
}

extern "C" void kernel_launch(void* const* d_in, const int* in_sizes, int n_in,
                              void* d_out, int out_size, void* d_ws, size_t ws_size,
                              hipStream_t stream) {
    const float* query   = (const float*)d_in[0];
    const float* support = (const float*)d_in[1];
    const int*   labels  = (const int*)d_in[2];
    const float* scale   = (const float*)d_in[5];
    float* out = (float*)d_out;
    float* ws  = (float*)d_ws;

    float* part = ws + OFF_PART;
    float* Kg   = ws + OFF_K;
    float* qp3  = ws + OFF_QP3;
    float* W    = ws + OFF_W;

    hipLaunchKernelGGL(gram_partial, dim3(64), dim3(256), 0, stream, support, part);
    hipLaunchKernelGGL(gram_reduce, dim3(62), dim3(256), 0, stream, part, Kg);
    hipLaunchKernelGGL(qp_solve, dim3(1), dim3(256), 0, stream, Kg, labels, qp3, out + NQ * NW);
    hipLaunchKernelGGL(w_kernel, dim3(DD / 256), dim3(256), 0, stream, support, qp3, W);
    hipLaunchKernelGGL(logits_kernel, dim3(NQ / 8), dim3(256), 0, stream, query, W, scale, out);
}

// Round 2
// 243.229 us; speedup vs baseline: 1.8785x; 1.8785x over previous
//
#include <hip/hip_runtime.h>

#define NS   125      // n_support
#define NW   5        // n_way
#define NQ   2048
#define DD   8192
#define CREG 0.1f
#define PGD_ITERS 40

// ws float offsets
#define OFF_PART 0          // 64 * 15625 = 1,000,000 floats
#define OFF_K    1000000    // 15625
#define OFF_QP3  1016000    // 625
#define OFF_W    1017000    // 5*8192 = 40960
// total ~4.24 MB of ws

// ---------------- Gram partials: K_partial[c] = S[:, c*128:(c+1)*128] chunk ----------------
__global__ __launch_bounds__(256) void gram_partial(const float* __restrict__ support,
                                                    float* __restrict__ part) {
    __shared__ __align__(16) float Sd[128 * 132];  // [d][s], pitch 132
    const int tid = threadIdx.x;
    const int blk = blockIdx.x;
    const int d0 = blk * 128;
    for (int idx = tid; idx < 128 * 128; idx += 256) {
        int s = idx >> 7, dj = idx & 127;
        float g = (s < NS) ? support[(size_t)s * DD + d0 + dj] : 0.f;
        Sd[dj * 132 + s] = g;
    }
    __syncthreads();
    const int tx = tid & 15, ty = tid >> 4;   // 8x8 output tile per thread over 128x128 (>=125)
    float acc[8][8];
#pragma unroll
    for (int i = 0; i < 8; i++)
#pragma unroll
        for (int j = 0; j < 8; j++) acc[i][j] = 0.f;
    for (int d = 0; d < 128; ++d) {
        float4 a0 = *(const float4*)&Sd[d * 132 + tx * 8];
        float4 a1 = *(const float4*)&Sd[d * 132 + tx * 8 + 4];
        float4 b0 = *(const float4*)&Sd[d * 132 + ty * 8];
        float4 b1 = *(const float4*)&Sd[d * 132 + ty * 8 + 4];
        float av[8] = {a0.x, a0.y, a0.z, a0.w, a1.x, a1.y, a1.z, a1.w};
        float bv[8] = {b0.x, b0.y, b0.z, b0.w, b1.x, b1.y, b1.z, b1.w};
#pragma unroll
        for (int i = 0; i < 8; i++)
#pragma unroll
            for (int j = 0; j < 8; j++) acc[i][j] += av[i] * bv[j];
    }
    float* dst = part + (size_t)blk * (NS * NS);
    for (int i = 0; i < 8; i++) {
        int gi = tx * 8 + i;
        if (gi >= NS) continue;
        for (int j = 0; j < 8; j++) {
            int gj = ty * 8 + j;
            if (gj < NS) dst[gi * NS + gj] = acc[i][j];
        }
    }
}

// ---------------- Reduce partials -> K ----------------
__global__ __launch_bounds__(256) void gram_reduce(const float* __restrict__ part,
                                                   float* __restrict__ Kg) {
    int t = blockIdx.x * 256 + threadIdx.x;
    if (t < NS * NS) {
        float s = 0.f;
        for (int c = 0; c < 64; ++c) s += part[(size_t)c * (NS * NS) + t];
        Kg[t] = s;
    }
}

// ---------------- QP via projected gradient descent (single block, 16 waves) ----------------
// min 0.5 z^T G z + e^T z,  G = kron(K,I5)+I,  s.t. z <= h (h = C*y1h), sum_a z[s,a] = 0
// eta = 1.9/(GershgorinRowSum+1): contraction ~max(1-1.9 lmin/LG, 1.9 lmax/LG - 1) ~= 0.30/iter.
// Layout: wave w of 16; p = w>>1 (8-way j-split, WAVE-UNIFORM -> all z reads broadcast);
// s = (w&1)*64 + lane. Waves 0,1 (p==0) own projection; z kept in their registers.
__global__ __launch_bounds__(1024) void qp_solve(const float* __restrict__ Kg,
                                                 const int* __restrict__ labels,
                                                 float* __restrict__ qp3,
                                                 float* __restrict__ outNumSv) {
    __shared__ __align__(16) float zbuf[2][NW][128];  // double-buffered z columns (pad s=125..127 = 0)
    __shared__ float red[8][1152];                    // partials: red[p][s*9 + a] (stride 9 -> conflict-free)
    __shared__ float rs[128];
    __shared__ float eta_sh;
    __shared__ int svcount;

    const int tid  = threadIdx.x;
    const int w    = tid >> 6;
    const int lane = tid & 63;
    const int p    = w >> 1;            // wave-uniform j-chunk
    const int s    = (w & 1) * 64 + lane;

    // K row chunk (16 cols) into registers
    float kr[16];
#pragma unroll
    for (int j = 0; j < 16; ++j) {
        int col = p * 16 + j;
        kr[j] = (s < NS && col < NS) ? Kg[s * NS + col] : 0.f;
    }
    // zero both z buffers (incl. padding)
    for (int idx = tid; idx < 2 * NW * 128; idx += 1024) ((float*)zbuf)[idx] = 0.f;
    if (tid == 0) svcount = 0;
    // Gershgorin partial row-sum
    float rsum = 0.f;
#pragma unroll
    for (int j = 0; j < 16; ++j) rsum += fabsf(kr[j]);
    red[p][s * 9] = rsum;
    __syncthreads();
    if (w < 2) {
        float t = 0.f;
#pragma unroll
        for (int pp = 0; pp < 8; ++pp) t += red[pp][s * 9];
        rs[s] = t;
    }
    __syncthreads();
    if (tid == 0) {
        float m = 0.f;
        for (int i = 0; i < NS; ++i) m = fmaxf(m, rs[i]);
        eta_sh = 1.9f / (m + 1.0f);   // G = kron(K,I5) + I ; L <= rowsum+1
    }
    __syncthreads();
    const float eta = eta_sh;
    const int lab = (s < NS) ? labels[s] : 0;
    float z[NW];
#pragma unroll
    for (int a = 0; a < NW; a++) z[a] = 0.f;

    for (int it = 0; it < PGD_ITERS; ++it) {
        const int cur = it & 1, nxt = cur ^ 1;
        // partial matvec over this wave's 16-j chunk; all z reads are wave-uniform broadcasts
        float acc[NW] = {0.f, 0.f, 0.f, 0.f, 0.f};
        const int jb0 = p * 16;
#pragma unroll
        for (int c = 0; c < 4; ++c) {
            const int jb = jb0 + c * 4;
            float4 z0 = *(const float4*)&zbuf[cur][0][jb];
            float4 z1 = *(const float4*)&zbuf[cur][1][jb];
            float4 z2 = *(const float4*)&zbuf[cur][2][jb];
            float4 z3 = *(const float4*)&zbuf[cur][3][jb];
            float4 z4 = *(const float4*)&zbuf[cur][4][jb];
            float k0 = kr[c * 4], k1 = kr[c * 4 + 1], k2 = kr[c * 4 + 2], k3 = kr[c * 4 + 3];
            acc[0] += k0 * z0.x + k1 * z0.y + k2 * z0.z + k3 * z0.w;
            acc[1] += k0 * z1.x + k1 * z1.y + k2 * z1.z + k3 * z1.w;
            acc[2] += k0 * z2.x + k1 * z2.y + k2 * z2.z + k3 * z2.w;
            acc[3] += k0 * z3.x + k1 * z3.y + k2 * z3.z + k3 * z3.w;
            acc[4] += k0 * z4.x + k1 * z4.y + k2 * z4.z + k3 * z4.w;
        }
        {
            float* myred = &red[p][s * 9];
            myred[0] = acc[0]; myred[1] = acc[1]; myred[2] = acc[2];
            myred[3] = acc[3]; myred[4] = acc[4];
        }
        __syncthreads();
        if (w < 2 && s < NS) {
            float kz[NW] = {0.f, 0.f, 0.f, 0.f, 0.f};
#pragma unroll
            for (int pp = 0; pp < 8; ++pp) {
                const float* rr = &red[pp][s * 9];
#pragma unroll
                for (int a = 0; a < NW; a++) kz[a] += rr[a];
            }
            float v[NW], h[NW];
#pragma unroll
            for (int a = 0; a < NW; a++) {
                float g = kz[a] + z[a] - ((a == lab) ? 1.f : 0.f);   // Gz + e
                v[a] = z[a] - eta * g;
                h[a] = (a == lab) ? CREG : 0.f;
            }
            // exact projection onto {sum_a z = 0, z <= h}: Newton on g(tau)=sum min(v-tau,h)
            float tau = fmaxf(fmaxf(fmaxf(v[0], v[1]), fmaxf(v[2], v[3])), v[4]);
#pragma unroll
            for (int n = 0; n < 7; ++n) {
                float g = 0.f, nf = 0.f;
#pragma unroll
                for (int a = 0; a < NW; a++) {
                    float d = v[a] - tau;
                    bool fr = (d <= h[a]);
                    g += fr ? d : h[a];
                    nf += fr ? 1.f : 0.f;
                }
                tau += g / nf;
            }
#pragma unroll
            for (int a = 0; a < NW; a++) {
                z[a] = fminf(v[a] - tau, h[a]);
                zbuf[nxt][a][s] = z[a];
            }
        }
        __syncthreads();
    }

    // epilogue
    if (w < 2 && s < NS) {
        float m = fmaxf(fmaxf(fmaxf(z[0], z[1]), fmaxf(z[2], z[3])), z[4]);
        if (m > 0.001f) atomicAdd(&svcount, 1);
#pragma unroll
        for (int a = 0; a < NW; a++) qp3[s * NW + a] = z[a];
    }
    __syncthreads();
    if (tid == 0) *outNumSv = (float)svcount;
}

// ---------------- W[a][d] = sum_s support[s][d] * qp3[s][a] ----------------
__global__ __launch_bounds__(256) void w_kernel(const float* __restrict__ support,
                                                const float* __restrict__ qp3,
                                                float* __restrict__ W) {
    __shared__ float q3[NS * NW];
    const int tid = threadIdx.x;
    for (int i = tid; i < NS * NW; i += 256) q3[i] = qp3[i];
    __syncthreads();
    const int d = blockIdx.x * 256 + tid;
    float acc[NW] = {0.f, 0.f, 0.f, 0.f, 0.f};
    for (int sld = 0; sld < NS; ++sld) {
        float sv = support[(size_t)sld * DD + d];
#pragma unroll
        for (int a = 0; a < NW; a++) acc[a] += sv * q3[sld * NW + a];
    }
#pragma unroll
    for (int a = 0; a < NW; a++) W[(size_t)a * DD + d] = acc[a];
}

// ---------------- logits[q][a] = scale * sum_d query[q][d] * W[a][d] ----------------
__global__ __launch_bounds__(256) void logits_kernel(const float* __restrict__ query,
                                                     const float* __restrict__ W,
                                                     const float* __restrict__ scale,
                                                     float* __restrict__ out) {
    const int tid = threadIdx.x;
    const int wave = tid >> 6, lane = tid & 63;
    const int q0 = blockIdx.x * 8 + wave * 2;
    const int q1 = q0 + 1;
    float a0[NW] = {0.f, 0.f, 0.f, 0.f, 0.f};
    float a1[NW] = {0.f, 0.f, 0.f, 0.f, 0.f};
    const float4* qp0 = (const float4*)(query + (size_t)q0 * DD);
    const float4* qp1 = (const float4*)(query + (size_t)q1 * DD);
    for (int it = 0; it < 32; ++it) {
        int dv = it * 64 + lane;  // float4 index, 2048 total
        float4 qv0 = qp0[dv];
        float4 qv1 = qp1[dv];
#pragma unroll
        for (int a = 0; a < NW; a++) {
            float4 wv = ((const float4*)(W + (size_t)a * DD))[dv];
            a0[a] += qv0.x * wv.x + qv0.y * wv.y + qv0.z * wv.z + qv0.w * wv.w;
            a1[a] += qv1.x * wv.x + qv1.y * wv.y + qv1.z * wv.z + qv1.w * wv.w;
        }
    }
#pragma unroll
    for (int off = 32; off; off >>= 1) {
#pragma unroll
        for (int a = 0; a < NW; a++) {
            a0[a] += __shfl_xor(a0[a], off);
            a1[a] += __shfl_xor(a1[a], off);
        }
    }
    if (lane == 0) {
        float sc = scale[0];
#pragma unroll
        for (int a = 0; a < NW; a++) out[q0 * NW + a] = sc * a0[a];
#pragma unroll
        for (int a = 0; a < NW; a++) out[q1 * NW + a] = sc * a1[a];
    }
}

extern "C" void kernel_launch(void* const* d_in, const int* in_sizes, int n_in,
                              void* d_out, int out_size, void* d_ws, size_t ws_size,
                              hipStream_t stream) {
    const float* query   = (const float*)d_in[0];
    const float* support = (const float*)d_in[1];
    const int*   labels  = (const int*)d_in[2];
    const float* scale   = (const float*)d_in[5];
    float* out = (float*)d_out;
    float* ws  = (float*)d_ws;

    float* part = ws + OFF_PART;
    float* Kg   = ws + OFF_K;
    float* qp3  = ws + OFF_QP3;
    float* W    = ws + OFF_W;

    hipLaunchKernelGGL(gram_partial, dim3(64), dim3(256), 0, stream, support, part);
    hipLaunchKernelGGL(gram_reduce, dim3(62), dim3(256), 0, stream, part, Kg);
    hipLaunchKernelGGL(qp_solve, dim3(1), dim3(1024), 0, stream, Kg, labels, qp3, out + NQ * NW);
    hipLaunchKernelGGL(w_kernel, dim3(DD / 256), dim3(256), 0, stream, support, qp3, W);
    hipLaunchKernelGGL(logits_kernel, dim3(NQ / 8), dim3(256), 0, stream, query, W, scale, out);
}

// Round 4
// 208.606 us; speedup vs baseline: 2.1902x; 1.1660x over previous
//
#include <hip/hip_runtime.h>

#define NS   125      // n_support
#define NW   5        // n_way
#define NQ   2048
#define DD   8192
#define CREG 0.1f
#define PGD_ITERS 24

// ws float offsets
#define OFF_PART 0          // 64 * 15625 = 1,000,000 floats
#define OFF_K    1000000    // 15625
#define OFF_QP3  1016000    // 625
#define OFF_W    1017000    // 5*8192 = 40960

// INJECTIVE swizzle: shift each 32-float s-group by +4*g words (g = s>>5).
// Group g occupies [36g, 36g+31] -- disjoint, max 139 -> pitch 140.
// tx-read start banks: (8tx + 4*(tx>>2)) % 32 covers all 32 banks 2x -> free.
__device__ __forceinline__ int spos(int s) { return s + ((s >> 5) << 2); }

// ---------------- Gram partials ----------------
__global__ __launch_bounds__(256) void gram_partial(const float* __restrict__ support,
                                                    float* __restrict__ part) {
    __shared__ __align__(16) float Sd[128 * 140];  // [d][spos(s)], pitch 140
    const int tid = threadIdx.x;
    const int blk = blockIdx.x;
    const int d0 = blk * 128;
    for (int idx = tid; idx < 128 * 128; idx += 256) {
        int s = idx >> 7, dj = idx & 127;
        float g = (s < NS) ? support[(size_t)s * DD + d0 + dj] : 0.f;
        Sd[dj * 140 + spos(s)] = g;
    }
    __syncthreads();
    const int tx = tid & 15, ty = tid >> 4;   // 8x8 output tile per thread
    const int xa = spos(tx * 8);              // still float4-aligned (multiple of 4)
    const int ya = spos(ty * 8);
    float acc[8][8];
#pragma unroll
    for (int i = 0; i < 8; i++)
#pragma unroll
        for (int j = 0; j < 8; j++) acc[i][j] = 0.f;
    for (int d = 0; d < 128; ++d) {
        float4 a0 = *(const float4*)&Sd[d * 140 + xa];
        float4 a1 = *(const float4*)&Sd[d * 140 + xa + 4];
        float4 b0 = *(const float4*)&Sd[d * 140 + ya];
        float4 b1 = *(const float4*)&Sd[d * 140 + ya + 4];
        float av[8] = {a0.x, a0.y, a0.z, a0.w, a1.x, a1.y, a1.z, a1.w};
        float bv[8] = {b0.x, b0.y, b0.z, b0.w, b1.x, b1.y, b1.z, b1.w};
#pragma unroll
        for (int i = 0; i < 8; i++)
#pragma unroll
            for (int j = 0; j < 8; j++) acc[i][j] += av[i] * bv[j];
    }
    float* dst = part + (size_t)blk * (NS * NS);
    for (int i = 0; i < 8; i++) {
        int gi = tx * 8 + i;
        if (gi >= NS) continue;
        for (int j = 0; j < 8; j++) {
            int gj = ty * 8 + j;
            if (gj < NS) dst[gi * NS + gj] = acc[i][j];
        }
    }
}

// ---------------- Reduce partials -> K ----------------
__global__ __launch_bounds__(256) void gram_reduce(const float* __restrict__ part,
                                                   float* __restrict__ Kg) {
    int t = blockIdx.x * 256 + threadIdx.x;
    if (t < NS * NS) {
        float s = 0.f;
        for (int c = 0; c < 64; ++c) s += part[(size_t)c * (NS * NS) + t];
        Kg[t] = s;
    }
}

// ---------------- QP via PGD, 4-wave minimal-LDS layout ----------------
// wave w = j-chunk [32w,32w+32); lane owns rows (lane, lane+64) for the matvec.
// z chunks disjoint across waves -> z read exactly once/iter (160 b128 total).
// Partials: red2[row*25 + w*5 + a] (25 coprime 32 -> conflict-free), projector
// (waves 0,1; row = 64w+lane) reads its 20 partials contiguously.
// K rows loaded via symmetry (K==K^T) for coalesced prologue.
__global__ __launch_bounds__(256) void qp_solve(const float* __restrict__ Kg,
                                                const int* __restrict__ labels,
                                                float* __restrict__ qp3,
                                                float* __restrict__ outNumSv) {
    __shared__ __align__(16) float zs[NW][128];   // z columns (rows 125..127 stay 0)
    __shared__ float red2[128 * 25];
    __shared__ float rsmax[2];
    __shared__ int svcount;

    const int tid  = threadIdx.x;
    const int w    = tid >> 6;
    const int lane = tid & 63;
    const int c0   = w * 32;
    const int r0   = lane, r1 = lane + 64;

    // K row chunks via symmetry: kr0[j] = K[r0][c0+j] = K[c0+j][r0] (coalesced)
    float kr0[32], kr1[32];
#pragma unroll
    for (int j = 0; j < 32; ++j) {
        const int col = c0 + j;
        const bool cv = (col < NS);
        kr0[j] = cv ? Kg[col * NS + r0] : 0.f;
        kr1[j] = (cv && r1 < NS) ? Kg[col * NS + r1] : 0.f;
    }
    // zero z buffer
    for (int idx = tid; idx < NW * 128; idx += 256) ((float*)zs)[idx] = 0.f;
    if (tid == 0) svcount = 0;
    // Gershgorin partial row-sums into a=0 slots
    float rsum0 = 0.f, rsum1 = 0.f;
#pragma unroll
    for (int j = 0; j < 32; ++j) { rsum0 += fabsf(kr0[j]); rsum1 += fabsf(kr1[j]); }
    red2[r0 * 25 + w * 5] = rsum0;
    red2[r1 * 25 + w * 5] = rsum1;
    __syncthreads();
    const int prow = w * 64 + lane;   // projector row for w<2
    if (w < 2) {
        const float* rr = &red2[prow * 25];
        float t = (prow < NS) ? rr[0] + rr[5] + rr[10] + rr[15] : 0.f;
#pragma unroll
        for (int off = 32; off; off >>= 1) t = fmaxf(t, __shfl_xor(t, off));
        if (lane == 0) rsmax[w] = t;
    }
    __syncthreads();
    const float eta = 1.9f / (fmaxf(rsmax[0], rsmax[1]) + 1.0f);  // G = kron(K,I5)+I
    const int lab = (w < 2 && prow < NS) ? labels[prow] : 0;
    float z[NW] = {0.f, 0.f, 0.f, 0.f, 0.f};

    for (int it = 0; it < PGD_ITERS; ++it) {
        float acc0[NW] = {0.f, 0.f, 0.f, 0.f, 0.f};
        float acc1[NW] = {0.f, 0.f, 0.f, 0.f, 0.f};
#pragma unroll
        for (int c = 0; c < 8; ++c) {
            const int jb = c0 + 4 * c;                 // wave-uniform -> broadcast b128
            float4 z0 = *(const float4*)&zs[0][jb];
            float4 z1 = *(const float4*)&zs[1][jb];
            float4 z2 = *(const float4*)&zs[2][jb];
            float4 z3 = *(const float4*)&zs[3][jb];
            float4 z4 = *(const float4*)&zs[4][jb];
            const float k00 = kr0[4*c], k01 = kr0[4*c+1], k02 = kr0[4*c+2], k03 = kr0[4*c+3];
            const float k10 = kr1[4*c], k11 = kr1[4*c+1], k12 = kr1[4*c+2], k13 = kr1[4*c+3];
            acc0[0] += k00*z0.x + k01*z0.y + k02*z0.z + k03*z0.w;
            acc0[1] += k00*z1.x + k01*z1.y + k02*z1.z + k03*z1.w;
            acc0[2] += k00*z2.x + k01*z2.y + k02*z2.z + k03*z2.w;
            acc0[3] += k00*z3.x + k01*z3.y + k02*z3.z + k03*z3.w;
            acc0[4] += k00*z4.x + k01*z4.y + k02*z4.z + k03*z4.w;
            acc1[0] += k10*z0.x + k11*z0.y + k12*z0.z + k13*z0.w;
            acc1[1] += k10*z1.x + k11*z1.y + k12*z1.z + k13*z1.w;
            acc1[2] += k10*z2.x + k11*z2.y + k12*z2.z + k13*z2.w;
            acc1[3] += k10*z3.x + k11*z3.y + k12*z3.z + k13*z3.w;
            acc1[4] += k10*z4.x + k11*z4.y + k12*z4.z + k13*z4.w;
        }
        {
            float* b0 = &red2[r0 * 25 + w * 5];
            b0[0] = acc0[0]; b0[1] = acc0[1]; b0[2] = acc0[2]; b0[3] = acc0[3]; b0[4] = acc0[4];
            float* b1 = &red2[r1 * 25 + w * 5];
            b1[0] = acc1[0]; b1[1] = acc1[1]; b1[2] = acc1[2]; b1[3] = acc1[3]; b1[4] = acc1[4];
        }
        __syncthreads();
        if (w < 2 && prow < NS) {
            const float* rr = &red2[prow * 25];
            float v[NW], h[NW];
#pragma unroll
            for (int a = 0; a < NW; a++) {
                float kz = rr[a] + rr[5 + a] + rr[10 + a] + rr[15 + a];
                float g = kz + z[a] - ((a == lab) ? 1.f : 0.f);   // Gz + e
                v[a] = z[a] - eta * g;
                h[a] = (a == lab) ? CREG : 0.f;
            }
            float tau = fmaxf(fmaxf(fmaxf(v[0], v[1]), fmaxf(v[2], v[3])), v[4]);
#pragma unroll
            for (int n = 0; n < 7; ++n) {
                float g = 0.f, nf = 0.f;
#pragma unroll
                for (int a = 0; a < NW; a++) {
                    float d = v[a] - tau;
                    bool fr = (d <= h[a]);
                    g += fr ? d : h[a];
                    nf += fr ? 1.f : 0.f;
                }
                tau += g / nf;
            }
#pragma unroll
            for (int a = 0; a < NW; a++) {
                z[a] = fminf(v[a] - tau, h[a]);
                zs[a][prow] = z[a];
            }
        }
        __syncthreads();
    }

    if (w < 2 && prow < NS) {
        float m = fmaxf(fmaxf(fmaxf(z[0], z[1]), fmaxf(z[2], z[3])), z[4]);
        if (m > 0.001f) atomicAdd(&svcount, 1);
#pragma unroll
        for (int a = 0; a < NW; a++) qp3[prow * NW + a] = z[a];
    }
    __syncthreads();
    if (tid == 0) *outNumSv = (float)svcount;
}

// ---------------- W[a][d] = sum_s support[s][d] * qp3[s][a] ----------------
__global__ __launch_bounds__(128) void w_kernel(const float* __restrict__ support,
                                                const float* __restrict__ qp3,
                                                float* __restrict__ W) {
    __shared__ float q3[NS * NW];
    const int tid = threadIdx.x;
    for (int i = tid; i < NS * NW; i += 128) q3[i] = qp3[i];
    __syncthreads();
    const int d = blockIdx.x * 128 + tid;
    float acc[NW] = {0.f, 0.f, 0.f, 0.f, 0.f};
    for (int sld = 0; sld < NS; ++sld) {
        float sv = support[(size_t)sld * DD + d];
#pragma unroll
        for (int a = 0; a < NW; a++) acc[a] += sv * q3[sld * NW + a];
    }
#pragma unroll
    for (int a = 0; a < NW; a++) W[(size_t)a * DD + d] = acc[a];
}

// ---------------- logits[q][a] = scale * sum_d query[q][d] * W[a][d] ----------------
__global__ __launch_bounds__(256) void logits_kernel(const float* __restrict__ query,
                                                     const float* __restrict__ W,
                                                     const float* __restrict__ scale,
                                                     float* __restrict__ out) {
    const int tid = threadIdx.x;
    const int wave = tid >> 6, lane = tid & 63;
    const int q0 = blockIdx.x * 8 + wave * 2;
    const int q1 = q0 + 1;
    float a0[NW] = {0.f, 0.f, 0.f, 0.f, 0.f};
    float a1[NW] = {0.f, 0.f, 0.f, 0.f, 0.f};
    const float4* qp0 = (const float4*)(query + (size_t)q0 * DD);
    const float4* qp1 = (const float4*)(query + (size_t)q1 * DD);
    for (int it = 0; it < 32; ++it) {
        int dv = it * 64 + lane;
        float4 qv0 = qp0[dv];
        float4 qv1 = qp1[dv];
#pragma unroll
        for (int a = 0; a < NW; a++) {
            float4 wv = ((const float4*)(W + (size_t)a * DD))[dv];
            a0[a] += qv0.x * wv.x + qv0.y * wv.y + qv0.z * wv.z + qv0.w * wv.w;
            a1[a] += qv1.x * wv.x + qv1.y * wv.y + qv1.z * wv.z + qv1.w * wv.w;
        }
    }
#pragma unroll
    for (int off = 32; off; off >>= 1) {
#pragma unroll
        for (int a = 0; a < NW; a++) {
            a0[a] += __shfl_xor(a0[a], off);
            a1[a] += __shfl_xor(a1[a], off);
        }
    }
    if (lane == 0) {
        float sc = scale[0];
#pragma unroll
        for (int a = 0; a < NW; a++) out[q0 * NW + a] = sc * a0[a];
#pragma unroll
        for (int a = 0; a < NW; a++) out[q1 * NW + a] = sc * a1[a];
    }
}

extern "C" void kernel_launch(void* const* d_in, const int* in_sizes, int n_in,
                              void* d_out, int out_size, void* d_ws, size_t ws_size,
                              hipStream_t stream) {
    const float* query   = (const float*)d_in[0];
    const float* support = (const float*)d_in[1];
    const int*   labels  = (const int*)d_in[2];
    const float* scale   = (const float*)d_in[5];
    float* out = (float*)d_out;
    float* ws  = (float*)d_ws;

    float* part = ws + OFF_PART;
    float* Kg   = ws + OFF_K;
    float* qp3  = ws + OFF_QP3;
    float* W    = ws + OFF_W;

    hipLaunchKernelGGL(gram_partial, dim3(64), dim3(256), 0, stream, support, part);
    hipLaunchKernelGGL(gram_reduce, dim3(62), dim3(256), 0, stream, part, Kg);
    hipLaunchKernelGGL(qp_solve, dim3(1), dim3(256), 0, stream, Kg, labels, qp3, out + NQ * NW);
    hipLaunchKernelGGL(w_kernel, dim3(DD / 128), dim3(128), 0, stream, support, qp3, W);
    hipLaunchKernelGGL(logits_kernel, dim3(NQ / 8), dim3(256), 0, stream, query, W, scale, out);
}

// Round 5
// 184.794 us; speedup vs baseline: 2.4725x; 1.1289x over previous
//
#include <hip/hip_runtime.h>

#define NS   125      // n_support
#define NW   5        // n_way
#define NQ   2048
#define DD   8192
#define CREG 0.1f
#define PGD_ITERS 16

// ws float offsets
#define OFF_PART 0          // 64 * 15625 = 1,000,000 floats
#define OFF_K    1000000    // 15625
#define OFF_QP3  1016000    // 625
#define OFF_W    1017000    // 5*8192 = 40960

// ---------------- Gram partials: block = (d-chunk c, quadrant qy, qz) ----------------
// Output quadrant [64qy,64qy+64) x [64qz,64qz+64) of slab c (d in [128c,128c+128)).
__global__ __launch_bounds__(256) void gram_partial(const float* __restrict__ support,
                                                    float* __restrict__ part) {
    __shared__ __align__(16) float As[128][68];  // [d][s-local], pitch 68 (2-way reads = free)
    __shared__ __align__(16) float Bs[128][68];
    const int tid = threadIdx.x;
    const int c  = blockIdx.x;
    const int qy = blockIdx.y, qz = blockIdx.z;
    const int d0 = c * 128;
    const int sy0 = qy * 64, sz0 = qz * 64;
    // stage: coalesced global reads (consecutive dj within an s-row)
    for (int idx = tid; idx < 64 * 128; idx += 256) {
        int sl = idx >> 7, dj = idx & 127;
        int sa = sy0 + sl, sb = sz0 + sl;
        As[dj][sl] = (sa < NS) ? support[(size_t)sa * DD + d0 + dj] : 0.f;
        Bs[dj][sl] = (sb < NS) ? support[(size_t)sb * DD + d0 + dj] : 0.f;
    }
    __syncthreads();
    const int tx = tid & 15, ty = tid >> 4;   // 4x4 tile
    float acc[4][4];
#pragma unroll
    for (int i = 0; i < 4; i++)
#pragma unroll
        for (int j = 0; j < 4; j++) acc[i][j] = 0.f;
#pragma unroll 4
    for (int d = 0; d < 128; ++d) {
        float4 a = *(const float4*)&As[d][tx * 4];
        float4 b = *(const float4*)&Bs[d][ty * 4];
        float av[4] = {a.x, a.y, a.z, a.w};
        float bv[4] = {b.x, b.y, b.z, b.w};
#pragma unroll
        for (int i = 0; i < 4; i++)
#pragma unroll
            for (int j = 0; j < 4; j++) acc[i][j] += av[i] * bv[j];
    }
    float* dst = part + (size_t)c * (NS * NS);
#pragma unroll
    for (int i = 0; i < 4; i++) {
        int gi = sy0 + tx * 4 + i;
        if (gi >= NS) continue;
#pragma unroll
        for (int j = 0; j < 4; j++) {
            int gj = sz0 + ty * 4 + j;
            if (gj < NS) dst[gi * NS + gj] = acc[i][j];
        }
    }
}

// ---------------- Reduce partials -> K ----------------
__global__ __launch_bounds__(256) void gram_reduce(const float* __restrict__ part,
                                                   float* __restrict__ Kg) {
    int t = blockIdx.x * 256 + threadIdx.x;
    if (t < NS * NS) {
        float s = 0.f;
        for (int c = 0; c < 64; ++c) s += part[(size_t)c * (NS * NS) + t];
        Kg[t] = s;
    }
}

// ---------------- QP via PGD: 1 barrier/iter, double-buffered z, all-wave projection ----
// wave w owns rows [32w,32w+32): 2 lanes/row (half = lane&1 covers cols [64*half,+64)).
// __shfl_xor(1) merges halves -> no LDS reduction slab. Owners (half==0) project
// (all 4 waves in parallel) and write z to the NEXT z-buffer; one barrier per iter.
__global__ __launch_bounds__(256) void qp_solve(const float* __restrict__ Kg,
                                                const int* __restrict__ labels,
                                                float* __restrict__ qp3,
                                                float* __restrict__ outNumSv) {
    __shared__ __align__(16) float zs[2][NW][128];  // rows 125..127 stay 0
    __shared__ float wmax[4];
    __shared__ int svcount;

    const int tid  = threadIdx.x;
    const int w    = tid >> 6;
    const int lane = tid & 63;
    const int r    = w * 32 + (lane >> 1);   // row 0..127
    const int half = lane & 1;
    const int cb   = half * 64;              // col base

    // K[r][cb..cb+64) via symmetry K==K^T (coalesced in r across lane pairs)
    float kr[64];
#pragma unroll
    for (int j = 0; j < 64; ++j) {
        int col = cb + j;
        kr[j] = (r < NS && col < NS) ? Kg[col * NS + r] : 0.f;
    }
    for (int idx = tid; idx < 2 * NW * 128; idx += 256) ((float*)zs)[idx] = 0.f;
    if (tid == 0) svcount = 0;
    // Gershgorin row-sum -> eta
    float rsum = 0.f;
#pragma unroll
    for (int j = 0; j < 64; ++j) rsum += fabsf(kr[j]);
    rsum += __shfl_xor(rsum, 1);             // both halves now hold full row sum
#pragma unroll
    for (int off = 32; off; off >>= 1) rsum = fmaxf(rsum, __shfl_xor(rsum, off));
    if (lane == 0) wmax[w] = rsum;
    __syncthreads();
    const float eta = 1.9f / (fmaxf(fmaxf(wmax[0], wmax[1]), fmaxf(wmax[2], wmax[3])) + 1.0f);
    const int lab = (r < NS) ? labels[r] : 0;
    float z[NW] = {0.f, 0.f, 0.f, 0.f, 0.f};  // owner copy (half==0 lanes)

    for (int it = 0; it < PGD_ITERS; ++it) {
        const int cur = it & 1, nxt = cur ^ 1;
        float acc[NW] = {0.f, 0.f, 0.f, 0.f, 0.f};
#pragma unroll
        for (int c = 0; c < 16; ++c) {
            const int jb = cb + 4 * c;       // 2 distinct addrs/wave -> 2-way broadcast (free)
            float4 z0 = *(const float4*)&zs[cur][0][jb];
            float4 z1 = *(const float4*)&zs[cur][1][jb];
            float4 z2 = *(const float4*)&zs[cur][2][jb];
            float4 z3 = *(const float4*)&zs[cur][3][jb];
            float4 z4 = *(const float4*)&zs[cur][4][jb];
            const float k0 = kr[4*c], k1 = kr[4*c+1], k2 = kr[4*c+2], k3 = kr[4*c+3];
            acc[0] += k0*z0.x + k1*z0.y + k2*z0.z + k3*z0.w;
            acc[1] += k0*z1.x + k1*z1.y + k2*z1.z + k3*z1.w;
            acc[2] += k0*z2.x + k1*z2.y + k2*z2.z + k3*z2.w;
            acc[3] += k0*z3.x + k1*z3.y + k2*z3.z + k3*z3.w;
            acc[4] += k0*z4.x + k1*z4.y + k2*z4.z + k3*z4.w;
        }
#pragma unroll
        for (int a = 0; a < NW; a++) acc[a] += __shfl_xor(acc[a], 1);  // merge halves
        if (half == 0 && r < NS) {
            float v[NW], h[NW];
#pragma unroll
            for (int a = 0; a < NW; a++) {
                float g = acc[a] + z[a] - ((a == lab) ? 1.f : 0.f);   // Gz + e
                v[a] = z[a] - eta * g;
                h[a] = (a == lab) ? CREG : 0.f;
            }
            // exact projection onto {sum_a z=0, z<=h}: Newton on g(tau)=sum min(v-tau,h)
            float tau = fmaxf(fmaxf(fmaxf(v[0], v[1]), fmaxf(v[2], v[3])), v[4]);
#pragma unroll
            for (int n = 0; n < 7; ++n) {
                float g = 0.f, nf = 0.f;
#pragma unroll
                for (int a = 0; a < NW; a++) {
                    float d = v[a] - tau;
                    bool fr = (d <= h[a]);
                    g += fr ? d : h[a];
                    nf += fr ? 1.f : 0.f;
                }
                tau += g / nf;
            }
#pragma unroll
            for (int a = 0; a < NW; a++) {
                z[a] = fminf(v[a] - tau, h[a]);
                zs[nxt][a][r] = z[a];
            }
        }
        __syncthreads();
    }

    if (half == 0 && r < NS) {
        float m = fmaxf(fmaxf(fmaxf(z[0], z[1]), fmaxf(z[2], z[3])), z[4]);
        if (m > 0.001f) atomicAdd(&svcount, 1);
#pragma unroll
        for (int a = 0; a < NW; a++) qp3[r * NW + a] = z[a];
    }
    __syncthreads();
    if (tid == 0) *outNumSv = (float)svcount;
}

// ---------------- W[a][d] = sum_s support[s][d] * qp3[s][a] ----------------
__global__ __launch_bounds__(128) void w_kernel(const float* __restrict__ support,
                                                const float* __restrict__ qp3,
                                                float* __restrict__ W) {
    __shared__ float q3[NS * NW];
    const int tid = threadIdx.x;
    for (int i = tid; i < NS * NW; i += 128) q3[i] = qp3[i];
    __syncthreads();
    const int d = blockIdx.x * 128 + tid;
    float acc[NW] = {0.f, 0.f, 0.f, 0.f, 0.f};
    for (int sld = 0; sld < NS; ++sld) {
        float sv = support[(size_t)sld * DD + d];
#pragma unroll
        for (int a = 0; a < NW; a++) acc[a] += sv * q3[sld * NW + a];
    }
#pragma unroll
    for (int a = 0; a < NW; a++) W[(size_t)a * DD + d] = acc[a];
}

// ---------------- logits[q][a] = scale * sum_d query[q][d] * W[a][d] ----------------
__global__ __launch_bounds__(256) void logits_kernel(const float* __restrict__ query,
                                                     const float* __restrict__ W,
                                                     const float* __restrict__ scale,
                                                     float* __restrict__ out) {
    const int tid = threadIdx.x;
    const int wave = tid >> 6, lane = tid & 63;
    const int q0 = blockIdx.x * 8 + wave * 2;
    const int q1 = q0 + 1;
    float a0[NW] = {0.f, 0.f, 0.f, 0.f, 0.f};
    float a1[NW] = {0.f, 0.f, 0.f, 0.f, 0.f};
    const float4* qp0 = (const float4*)(query + (size_t)q0 * DD);
    const float4* qp1 = (const float4*)(query + (size_t)q1 * DD);
    for (int it = 0; it < 32; ++it) {
        int dv = it * 64 + lane;
        float4 qv0 = qp0[dv];
        float4 qv1 = qp1[dv];
#pragma unroll
        for (int a = 0; a < NW; a++) {
            float4 wv = ((const float4*)(W + (size_t)a * DD))[dv];
            a0[a] += qv0.x * wv.x + qv0.y * wv.y + qv0.z * wv.z + qv0.w * wv.w;
            a1[a] += qv1.x * wv.x + qv1.y * wv.y + qv1.z * wv.z + qv1.w * wv.w;
        }
    }
#pragma unroll
    for (int off = 32; off; off >>= 1) {
#pragma unroll
        for (int a = 0; a < NW; a++) {
            a0[a] += __shfl_xor(a0[a], off);
            a1[a] += __shfl_xor(a1[a], off);
        }
    }
    if (lane == 0) {
        float sc = scale[0];
#pragma unroll
        for (int a = 0; a < NW; a++) out[q0 * NW + a] = sc * a0[a];
#pragma unroll
        for (int a = 0; a < NW; a++) out[q1 * NW + a] = sc * a1[a];
    }
}

extern "C" void kernel_launch(void* const* d_in, const int* in_sizes, int n_in,
                              void* d_out, int out_size, void* d_ws, size_t ws_size,
                              hipStream_t stream) {
    const float* query   = (const float*)d_in[0];
    const float* support = (const float*)d_in[1];
    const int*   labels  = (const int*)d_in[2];
    const float* scale   = (const float*)d_in[5];
    float* out = (float*)d_out;
    float* ws  = (float*)d_ws;

    float* part = ws + OFF_PART;
    float* Kg   = ws + OFF_K;
    float* qp3  = ws + OFF_QP3;
    float* W    = ws + OFF_W;

    hipLaunchKernelGGL(gram_partial, dim3(64, 2, 2), dim3(256), 0, stream, support, part);
    hipLaunchKernelGGL(gram_reduce, dim3(62), dim3(256), 0, stream, part, Kg);
    hipLaunchKernelGGL(qp_solve, dim3(1), dim3(256), 0, stream, Kg, labels, qp3, out + NQ * NW);
    hipLaunchKernelGGL(w_kernel, dim3(DD / 128), dim3(128), 0, stream, support, qp3, W);
    hipLaunchKernelGGL(logits_kernel, dim3(NQ / 8), dim3(256), 0, stream, query, W, scale, out);
}